// Round 8
// baseline (233.191 us; speedup 1.0000x reference)
//
#include <hip/hip_runtime.h>
#include <hip/hip_bf16.h>
#include <math.h>

#define B_ 64
#define N_ 64
#define C_ 8
#define F_ 256
#define K_ 2048    // C_*F_
#define NO_ 2048   // OC_*OF_
#define M_TOT 4160 // 64 (zx rows) + 4096 (zn rows)

typedef __attribute__((ext_vector_type(8))) short bf16x8;  // 8 bf16 = 4 VGPRs
typedef __attribute__((ext_vector_type(4))) float f32x4;

// ---------------------------------------------------------------------------
// FUSED PASS 1 (single read of nb):
//  range0 (512 blocks): per (b, chunk of 8 n); each wave owns 2 n rows.
//    For each row: load 2048 f (8 float4/lane), s2 = dot(row, w2sum) via
//    butterfly shuffle (no LDS, no barrier), then t_reg += row * s2 while the
//    row is still in registers. Write per-wave t-partial (32 partials per b).
//  range1 (64 blocks): s1[b] reduction.
//  range2 (4096 blocks): Wc fp32 -> bf16.
__global__ __launch_bounds__(256) void fuse1_k(const float* __restrict__ x,
        const float* __restrict__ nb, const float* __restrict__ W1,
        const float* __restrict__ W2, const float* __restrict__ Wc,
        float* __restrict__ s1, float* __restrict__ partial,
        __hip_bfloat16* __restrict__ Bbuf) {
    int blk = blockIdx.x;
    int tid = threadIdx.x;
    if (blk < 512) {
        int b = blk >> 3, ch = blk & 7;
        int wave = tid >> 6, lane = tid & 63;
        int n0 = ch * 8 + wave * 2;
        // w2sum4[l] = sum_c W2[c*256 + lane*4 + l]
        float4 w2sum4 = make_float4(0.f, 0.f, 0.f, 0.f);
        #pragma unroll
        for (int c = 0; c < C_; ++c) {
            float4 w = *(const float4*)(W2 + c * F_ + lane * 4);
            w2sum4.x += w.x; w2sum4.y += w.y; w2sum4.z += w.z; w2sum4.w += w.w;
        }
        float4 t_reg[8];
        #pragma unroll
        for (int q = 0; q < 8; ++q) t_reg[q] = make_float4(0.f, 0.f, 0.f, 0.f);
        #pragma unroll
        for (int n = 0; n < 2; ++n) {
            const float* row = nb + ((size_t)(b * N_ + n0 + n)) * K_;
            float4 r[8];
            #pragma unroll
            for (int q = 0; q < 8; ++q)
                r[q] = *(const float4*)(row + q * F_ + lane * 4);
            float4 cs = make_float4(0.f, 0.f, 0.f, 0.f);
            #pragma unroll
            for (int q = 0; q < 8; ++q) {
                cs.x += r[q].x; cs.y += r[q].y; cs.z += r[q].z; cs.w += r[q].w;
            }
            float dot = cs.x * w2sum4.x + cs.y * w2sum4.y
                      + cs.z * w2sum4.z + cs.w * w2sum4.w;
            #pragma unroll
            for (int off = 1; off < 64; off <<= 1)
                dot += __shfl_xor(dot, off, 64);
            // dot == s2[b, n0+n] on every lane
            #pragma unroll
            for (int q = 0; q < 8; ++q) {
                t_reg[q].x += r[q].x * dot;
                t_reg[q].y += r[q].y * dot;
                t_reg[q].z += r[q].z * dot;
                t_reg[q].w += r[q].w * dot;
            }
        }
        int wch = ch * 4 + wave;  // 0..31
        float* pdst = partial + ((size_t)(b * 32 + wch)) * K_;
        #pragma unroll
        for (int q = 0; q < 8; ++q)
            *(float4*)(pdst + q * F_ + lane * 4) = t_reg[q];
        return;
    }
    if (blk < 512 + B_) {
        int b = blk - 512;
        const float* base = x + (size_t)b * K_;
        float wsum = 0.f;
        #pragma unroll
        for (int k = 0; k < C_; ++k) wsum += W1[k * F_ + tid];
        float cs = 0.f;
        #pragma unroll
        for (int c = 0; c < C_; ++c) cs += base[c * F_ + tid];
        float val = cs * wsum;
        #pragma unroll
        for (int off = 32; off > 0; off >>= 1) val += __shfl_down(val, off, 64);
        __shared__ float wred[4];
        int w = tid >> 6;
        if ((tid & 63) == 0) wred[w] = val;
        __syncthreads();
        if (tid == 0) s1[b] = wred[0] + wred[1] + wred[2] + wred[3];
        return;
    }
    {
        int i = (blk - (512 + B_)) * 1024 + tid * 4;
        float4 v = *(const float4*)(Wc + i);
        Bbuf[i + 0] = __float2bfloat16(v.x);
        Bbuf[i + 1] = __float2bfloat16(v.y);
        Bbuf[i + 2] = __float2bfloat16(v.z);
        Bbuf[i + 3] = __float2bfloat16(v.w);
    }
}

// ---------------------------------------------------------------------------
// t[i] = s1[b] * sum_{w<32} partial[(b*32+w)*2048 + e];  i = b*2048 + e
__global__ __launch_bounds__(256) void reduce_t_k(const float* __restrict__ partial,
        const float* __restrict__ s1, float* __restrict__ t) {
    int i = blockIdx.x * 256 + threadIdx.x;
    int b = i >> 11, e = i & 2047;
    const float* p = partial + (size_t)(b * 32) * K_ + e;
    float acc = 0.f;
    #pragma unroll
    for (int w = 0; w < 32; ++w) acc += p[(size_t)w * K_];
    t[i] = acc * s1[b];
}

// ---------------------------------------------------------------------------
// rdenom[b,a,d] = 1 / (1e-7 + sum_c |sgnroot(x_a t_d + x_d t_a)|)
__global__ __launch_bounds__(256) void denom_k(const float* __restrict__ x,
        const float* __restrict__ t, float* __restrict__ rdenom) {
    int blk = blockIdx.x;  // b*F_ + a
    int b = blk >> 8, a = blk & 255;
    int d = threadIdx.x;
    float acc = 1e-7f;
    #pragma unroll
    for (int c = 0; c < C_; ++c) {
        size_t o = ((size_t)b * C_ + c) * F_;
        float xa = x[o + a], ta = t[o + a];
        float xd = x[o + d], td = t[o + d];
        float v = xa * td + xd * ta;
        float r = __builtin_amdgcn_sqrtf(fmaxf(fabsf(v), 1e-8f));
        acc += (v != 0.f) ? r : 0.f;
    }
    rdenom[(size_t)blk * F_ + d] = __builtin_amdgcn_rcpf(acc);
}

__device__ __forceinline__ float sgnroot_dev(float v) {
    float r = __builtin_amdgcn_sqrtf(fmaxf(fabsf(v), 1e-8f));
    return (v > 0.f) ? r : ((v < 0.f) ? -r : 0.f);
}

// ---------------------------------------------------------------------------
// Fused zx+zn via MFMA. One block per (b,c).
#define ZNX_PAD 264  // row STRIDE in bf16: 256 data + 8 pad
__global__ __launch_bounds__(256) void znx_k(const float* __restrict__ x,
        const float* __restrict__ t, const float* __restrict__ rdenom,
        const float* __restrict__ nb, __hip_bfloat16* __restrict__ Abuf) {
    int bc = blockIdx.x;
    int b = bc >> 3, c = bc & 7;
    int tid = threadIdx.x;
    int wave = tid >> 6, lane = tid & 63;
    __shared__ float xs[F_], ts[F_];
    __shared__ __hip_bfloat16 nbB[80 * ZNX_PAD];  // 42240 B

    xs[tid] = x[(size_t)bc * F_ + tid];
    ts[tid] = t[(size_t)bc * F_ + tid];
    {
        int r = tid >> 2, cs0 = (tid & 3) * 64;
        const float* src = nb + (((size_t)(b * N_ + r)) * C_ + c) * F_ + cs0;
        __hip_bfloat16* dst = nbB + r * ZNX_PAD + cs0;
        #pragma unroll
        for (int j = 0; j < 64; j += 4) {
            float4 v = *(const float4*)(src + j);
            dst[j + 0] = __float2bfloat16(v.x);
            dst[j + 1] = __float2bfloat16(v.y);
            dst[j + 2] = __float2bfloat16(v.z);
            dst[j + 3] = __float2bfloat16(v.w);
        }
    }
    if (tid < 64) {
        float4 v = *(const float4*)(x + (size_t)bc * F_ + tid * 4);
        __hip_bfloat16* dst = nbB + 64 * ZNX_PAD + tid * 4;
        dst[0] = __float2bfloat16(v.x);
        dst[1] = __float2bfloat16(v.y);
        dst[2] = __float2bfloat16(v.z);
        dst[3] = __float2bfloat16(v.w);
    }
    {
        __hip_bfloat16 z = __float2bfloat16(0.f);
        #pragma unroll
        for (int j = 0; j < 16; ++j) {
            int o = 65 * ZNX_PAD + tid * 16 + j;
            if (o < 80 * ZNX_PAD) nbB[o] = z;
        }
    }
    __syncthreads();

    const int aq = lane & 15;
    const int dq = lane >> 4;
    #pragma unroll
    for (int atile = 0; atile < 4; ++atile) {
        int a = wave * 64 + atile * 16 + aq;
        float xa = xs[a], ta = ts[a];
        const float* drow = rdenom + ((size_t)b * F_ + a) * F_;
        f32x4 acc[5] = {};
        #pragma unroll
        for (int kc = 0; kc < 8; ++kc) {
            int d0 = kc * 32 + dq * 8;
            float4 xv0 = *(const float4*)(xs + d0);
            float4 xv1 = *(const float4*)(xs + d0 + 4);
            float4 tv0 = *(const float4*)(ts + d0);
            float4 tv1 = *(const float4*)(ts + d0 + 4);
            float4 dn0 = *(const float4*)(drow + d0);
            float4 dn1 = *(const float4*)(drow + d0 + 4);
            float xv[8] = {xv0.x, xv0.y, xv0.z, xv0.w, xv1.x, xv1.y, xv1.z, xv1.w};
            float tv[8] = {tv0.x, tv0.y, tv0.z, tv0.w, tv1.x, tv1.y, tv1.z, tv1.w};
            float dn[8] = {dn0.x, dn0.y, dn0.z, dn0.w, dn1.x, dn1.y, dn1.z, dn1.w};
            union { bf16x8 v; __hip_bfloat16 h[8]; } bu;
            #pragma unroll
            for (int j = 0; j < 8; ++j) {
                float g = sgnroot_dev(xa * tv[j] + xv[j] * ta);
                bu.h[j] = __float2bfloat16(g * dn[j]);   // dn = 1/denom
            }
            #pragma unroll
            for (int mt = 0; mt < 5; ++mt) {
                bf16x8 af = *(const bf16x8*)(nbB + (mt * 16 + aq) * ZNX_PAD
                                             + kc * 32 + dq * 8);
                acc[mt] = __builtin_amdgcn_mfma_f32_16x16x32_bf16(
                    af, bu.v, acc[mt], 0, 0, 0);
            }
        }
        int colA = c * F_ + a;
        #pragma unroll
        for (int mt = 0; mt < 4; ++mt) {
            int row = 64 + b * N_ + mt * 16 + dq * 4;
            #pragma unroll
            for (int i = 0; i < 4; ++i)
                Abuf[(size_t)(row + i) * K_ + colA] = __float2bfloat16(acc[mt][i]);
        }
        if (dq == 0)
            Abuf[(size_t)b * K_ + colA] = __float2bfloat16(acc[4][0]);
    }
}

// ---------------------------------------------------------------------------
// C[M_TOT, 2048] = A[M_TOT, 2048] @ B[2048, 2048]^T, bf16 in, fp32 out.
// Swizzled row-major LDS (conflict-free reads + coalesced staging, R7).
__global__ __launch_bounds__(256) void gemm_bf16_k(
        const __hip_bfloat16* __restrict__ A,
        const __hip_bfloat16* __restrict__ Bm,
        float* __restrict__ Cm) {
    __shared__ char ldsA[8192] __attribute__((aligned(16)));
    __shared__ char ldsB[8192] __attribute__((aligned(16)));
    const int t = threadIdx.x;
    const int wave = t >> 6;
    const int lane = t & 63;
    const int col0 = blockIdx.x * 128;
    const int row0 = blockIdx.y * 128;
    const int wrow0 = (wave & 1) * 64;
    const int wcol0 = (wave >> 1) * 64;
    const int aq = lane & 15;
    const int dq = lane >> 4;

    const int rA0 = t >> 2;
    const int kcs = ((t & 3) - ((t >> 3) & 3)) & 3;
    const int kc = kcs * 8;
    const int grA0 = min(row0 + rA0, M_TOT - 1);
    const int grA1 = min(row0 + rA0 + 64, M_TOT - 1);
    const int gcB0 = col0 + rA0;
    const int gcB1 = col0 + rA0 + 64;
    char* lA0 = ldsA + wave * 1024;
    char* lA1 = ldsA + 4096 + wave * 1024;
    char* lB0 = ldsB + wave * 1024;
    char* lB1 = ldsB + 4096 + wave * 1024;

    const int swz = ((dq + (aq >> 1)) & 3) * 16;

    f32x4 acc[4][4] = {};

    for (int k0 = 0; k0 < K_; k0 += 32) {
        __syncthreads();
        __builtin_amdgcn_global_load_lds(
            (const __attribute__((address_space(1))) void*)(A + (size_t)grA0 * K_ + k0 + kc),
            (__attribute__((address_space(3))) void*)lA0, 16, 0, 0);
        __builtin_amdgcn_global_load_lds(
            (const __attribute__((address_space(1))) void*)(A + (size_t)grA1 * K_ + k0 + kc),
            (__attribute__((address_space(3))) void*)lA1, 16, 0, 0);
        __builtin_amdgcn_global_load_lds(
            (const __attribute__((address_space(1))) void*)(Bm + (size_t)gcB0 * K_ + k0 + kc),
            (__attribute__((address_space(3))) void*)lB0, 16, 0, 0);
        __builtin_amdgcn_global_load_lds(
            (const __attribute__((address_space(1))) void*)(Bm + (size_t)gcB1 * K_ + k0 + kc),
            (__attribute__((address_space(3))) void*)lB1, 16, 0, 0);
        __syncthreads();

        bf16x8 af[4], bf[4];
        #pragma unroll
        for (int rb = 0; rb < 4; ++rb)
            af[rb] = *(const bf16x8*)(ldsA + (wrow0 + rb * 16 + aq) * 64 + swz);
        #pragma unroll
        for (int cb = 0; cb < 4; ++cb)
            bf[cb] = *(const bf16x8*)(ldsB + (wcol0 + cb * 16 + aq) * 64 + swz);
        #pragma unroll
        for (int rb = 0; rb < 4; ++rb)
            #pragma unroll
            for (int cb = 0; cb < 4; ++cb)
                acc[rb][cb] = __builtin_amdgcn_mfma_f32_16x16x32_bf16(
                    af[rb], bf[cb], acc[rb][cb], 0, 0, 0);
    }

    #pragma unroll
    for (int rb = 0; rb < 4; ++rb) {
        int rowbase = row0 + wrow0 + rb * 16 + (lane >> 4) * 4;
        #pragma unroll
        for (int cb = 0; cb < 4; ++cb) {
            int col = col0 + wcol0 + cb * 16 + (lane & 15);
            #pragma unroll
            for (int i = 0; i < 4; ++i) {
                int row = rowbase + i;
                if (row < M_TOT)
                    Cm[(size_t)row * NO_ + col] = acc[rb][cb][i];
            }
        }
    }
}

// ---------------------------------------------------------------------------
extern "C" void kernel_launch(void* const* d_in, const int* in_sizes, int n_in,
                              void* d_out, int out_size, void* d_ws, size_t ws_size,
                              hipStream_t stream) {
    const float* x  = (const float*)d_in[0];
    const float* nb = (const float*)d_in[1];
    const float* W1 = (const float*)d_in[2];
    const float* W2 = (const float*)d_in[3];
    const float* Wc = (const float*)d_in[4];
    float* out = (float*)d_out;
    float* ws = (float*)d_ws;

    // workspace (f32 offsets); scratch4M shared by partial(fuse1/reduce) then
    // rden(denom/znx) -- sequentially dead, safe. Total ~42.7 MB.
    float* s1      = ws;            // 64
    float* t       = ws + 64;       // 131072
    float* scratch = ws + 131200;   // 4194304 (partial OR rden)
    __hip_bfloat16* Abuf = (__hip_bfloat16*)(ws + 4325504);  // 4160*2048 bf16
    __hip_bfloat16* Bbuf = (__hip_bfloat16*)(ws + 8585344);  // 2048*2048 bf16

    hipLaunchKernelGGL(fuse1_k, dim3(512 + B_ + (K_ * NO_) / 1024), dim3(256),
                       0, stream, x, nb, W1, W2, Wc, s1, scratch, Bbuf);
    hipLaunchKernelGGL(reduce_t_k, dim3(512), dim3(256), 0, stream,
                       scratch, s1, t);
    hipLaunchKernelGGL(denom_k, dim3(B_ * F_), dim3(256), 0, stream, x, t, scratch);
    hipLaunchKernelGGL(znx_k, dim3(B_ * C_), dim3(256), 0, stream,
                       x, t, scratch, nb, Abuf);
    hipLaunchKernelGGL(gemm_bf16_k, dim3(16, 33), dim3(256), 0, stream,
                       Abuf, Bbuf, out);
}